// Round 1
// baseline (880.240 us; speedup 1.0000x reference)
//
#include <hip/hip_runtime.h>
#include <hip/hip_bf16.h>

#define BATCH 32
#define DIM 4096
#define NH 32
#define NKV 8
#define HD 128
#define CTX 4096          // start_pos + s
#define NEWT 4095         // start_pos (new k/v goes here)
#define SM_SCALE 0.08838834764831845f  // 1/sqrt(128)

// C[b][c] += sum_{k in [k0, k0+kchunk)} A[b][k] * W[k][c]
// A: (32, K) row-major, W: (K, N) row-major. Atomic accumulate (k-split).
__global__ __launch_bounds__(256) void gemm32_kernel(
    const float* __restrict__ A, const float* __restrict__ W,
    float* __restrict__ C, int K, int N, int kchunk) {
  int c = blockIdx.x * 256 + threadIdx.x;
  int k0 = blockIdx.y * kchunk;
  float acc[BATCH];
#pragma unroll
  for (int b = 0; b < BATCH; ++b) acc[b] = 0.f;
  const float* Wp = W + (size_t)k0 * N + c;
  const float* Ap = A + k0;
#pragma unroll 4
  for (int k = 0; k < kchunk; ++k) {
    float wv = Wp[(size_t)k * N];          // coalesced vector load
#pragma unroll
    for (int b = 0; b < BATCH; ++b)
      acc[b] += Ap[b * K + k] * wv;        // uniform -> scalar loads
  }
#pragma unroll
  for (int b = 0; b < BATCH; ++b) atomicAdd(&C[b * N + c], acc[b]);
}

// RoPE in-place on ws_q (32 x 32 x 64 pairs) and ws_k (32 x 8 x 64 pairs)
__global__ __launch_bounds__(256) void rope_kernel(
    float* __restrict__ q, float* __restrict__ k,
    const float* __restrict__ cos_t, const float* __restrict__ sin_t) {
  int idx = blockIdx.x * 256 + threadIdx.x;   // pair index, 65536 total for q
  int p = idx & 63;
  float c = cos_t[p], s = sin_t[p];
  float2 v = ((float2*)q)[idx];
  float2 o;
  o.x = v.x * c - v.y * s;
  o.y = v.x * s + v.y * c;
  ((float2*)q)[idx] = o;
  if (idx < BATCH * NKV * 64) {
    float2 vk = ((float2*)k)[idx];
    float2 ok;
    ok.x = vk.x * c - vk.y * s;
    ok.y = vk.x * s + vk.y * c;
    ((float2*)k)[idx] = ok;
  }
}

// One block per (b, kv_head). 512 threads. Computes 4 rep heads.
__global__ __launch_bounds__(512) void attn_kernel(
    const float* __restrict__ q,        // (B, NH*HD) roped
    const float* __restrict__ kcache,   // (B, 4096, NKV, HD)
    const float* __restrict__ vcache,   // (B, 4096, NKV, HD)
    const float* __restrict__ knew,     // (B, NKV*HD) roped
    const float* __restrict__ vnew,     // (B, NKV*HD)
    float* __restrict__ out) {          // (B, NH*HD)
  __shared__ float sc[4 * CTX];         // 64 KB: scores then probs; reused for reduce
  int b = blockIdx.x >> 3, h = blockIdx.x & 7;
  int tid = threadIdx.x;
  int wave = tid >> 6, sub = tid & 63;

  // ---- phase 1: scores[r][t] = q[r] . K[t] * scale ----
  int tg = tid >> 4;     // t-group 0..31
  int lig = tid & 15;    // lane in group; covers 8 d's
  float qreg[4][8];
#pragma unroll
  for (int r = 0; r < 4; ++r)
#pragma unroll
    for (int j = 0; j < 8; ++j)
      qreg[r][j] = q[b * (NH * HD) + (h * 4 + r) * HD + lig * 8 + j];

  const float* kbase = kcache + ((size_t)b * 4096 * NKV + h) * HD;
  const float* knrow = knew + (b * NKV + h) * HD;
  for (int t0 = 0; t0 < CTX; t0 += 32) {
    int t = t0 + tg;
    const float* krow = (t < NEWT) ? (kbase + (size_t)t * (NKV * HD)) : knrow;
    float4 ka = *(const float4*)(krow + lig * 8);
    float4 kb = *(const float4*)(krow + lig * 8 + 4);
    float part[4];
#pragma unroll
    for (int r = 0; r < 4; ++r) {
      part[r] = ka.x * qreg[r][0] + ka.y * qreg[r][1] + ka.z * qreg[r][2] + ka.w * qreg[r][3]
              + kb.x * qreg[r][4] + kb.y * qreg[r][5] + kb.z * qreg[r][6] + kb.w * qreg[r][7];
#pragma unroll
      for (int off = 8; off >= 1; off >>= 1)
        part[r] += __shfl_xor(part[r], off);
    }
    if (lig == 0) {
#pragma unroll
      for (int r = 0; r < 4; ++r) sc[r * CTX + t] = part[r] * SM_SCALE;
    }
  }
  __syncthreads();

  // ---- softmax per rep (waves 0..3), normalization folded into probs ----
  if (wave < 4) {
    int r = wave;
    float m = -1e30f;
    for (int i = sub; i < CTX; i += 64) m = fmaxf(m, sc[r * CTX + i]);
#pragma unroll
    for (int off = 32; off >= 1; off >>= 1) m = fmaxf(m, __shfl_xor(m, off));
    float ssum = 0.f;
    for (int i = sub; i < CTX; i += 64) {
      float pv = __expf(sc[r * CTX + i] - m);
      sc[r * CTX + i] = pv;
      ssum += pv;
    }
#pragma unroll
    for (int off = 32; off >= 1; off >>= 1) ssum += __shfl_xor(ssum, off);
    float inv = 1.f / ssum;
    for (int i = sub; i < CTX; i += 64) sc[r * CTX + i] *= inv;
  }
  __syncthreads();

  // ---- phase 2: out[r][d] = sum_t p[r][t] * V[t][d] ----
  int dg = tid & 31;     // float4 index over d (32*4 = 128)
  int tg2 = tid >> 5;    // 0..15
  float4 acc[4];
#pragma unroll
  for (int r = 0; r < 4; ++r) acc[r] = make_float4(0.f, 0.f, 0.f, 0.f);
  const float* vbase = vcache + ((size_t)b * 4096 * NKV + h) * HD;
  const float* vnrow = vnew + (b * NKV + h) * HD;
  for (int t0 = 0; t0 < CTX; t0 += 16) {
    int t = t0 + tg2;
    const float* vrow = (t < NEWT) ? (vbase + (size_t)t * (NKV * HD)) : vnrow;
    float4 vv = *(const float4*)(vrow + dg * 4);
#pragma unroll
    for (int r = 0; r < 4; ++r) {
      float pv = sc[r * CTX + t];   // LDS broadcast
      acc[r].x += pv * vv.x;
      acc[r].y += pv * vv.y;
      acc[r].z += pv * vv.z;
      acc[r].w += pv * vv.w;
    }
  }
  __syncthreads();   // everyone done reading probs; reuse sc as reduce buffer

  float* red = sc;   // [4][16][128]
#pragma unroll
  for (int r = 0; r < 4; ++r)
    *(float4*)&red[((r * 16 + tg2) << 7) + dg * 4] = acc[r];
  __syncthreads();
  {
    int r = tid >> 7, d = tid & 127;
    float s = 0.f;
#pragma unroll
    for (int g = 0; g < 16; ++g) s += red[((r * 16 + g) << 7) + d];
    out[b * (NH * HD) + (h * 4 + r) * HD + d] = s;
  }
}

extern "C" void kernel_launch(void* const* d_in, const int* in_sizes, int n_in,
                              void* d_out, int out_size, void* d_ws, size_t ws_size,
                              hipStream_t stream) {
  const float* x  = (const float*)d_in[0];
  const float* wq = (const float*)d_in[1];
  const float* wk = (const float*)d_in[2];
  const float* wv = (const float*)d_in[3];
  const float* wo = (const float*)d_in[4];
  const float* ck = (const float*)d_in[5];
  const float* cv = (const float*)d_in[6];
  const float* fc = (const float*)d_in[7];
  const float* fs = (const float*)d_in[8];
  float* out = (float*)d_out;

  float* ws   = (float*)d_ws;
  float* ws_q = ws;             // 32*4096 = 131072 floats
  float* ws_k = ws + 131072;    // 32*1024
  float* ws_v = ws + 163840;    // 32*1024
  float* ws_a = ws + 196608;    // 32*4096 (attn output, fully overwritten)

  // zero atomic-accumulation targets
  hipMemsetAsync(ws, 0, 196608 * sizeof(float), stream);
  hipMemsetAsync(d_out, 0, (size_t)out_size * sizeof(float), stream);

  // QKV projections (k-split 16)
  gemm32_kernel<<<dim3(16, 16), 256, 0, stream>>>(x, wq, ws_q, DIM, NH * HD, 256);
  gemm32_kernel<<<dim3(4, 16), 256, 0, stream>>>(x, wk, ws_k, DIM, NKV * HD, 256);
  gemm32_kernel<<<dim3(4, 16), 256, 0, stream>>>(x, wv, ws_v, DIM, NKV * HD, 256);

  // RoPE on q and new k
  rope_kernel<<<256, 256, 0, stream>>>(ws_q, ws_k, fc, fs);

  // decode attention: one block per (b, kv head)
  attn_kernel<<<256, 512, 0, stream>>>(ws_q, ck, cv, ws_k, ws_v, ws_a);

  // output projection
  gemm32_kernel<<<dim3(16, 16), 256, 0, stream>>>(ws_a, wo, out, DIM, DIM, 256);
}

// Round 2
// 562.772 us; speedup vs baseline: 1.5641x; 1.5641x over previous
//
#include <hip/hip_runtime.h>
#include <hip/hip_bf16.h>

#define BATCH 32
#define DIM 4096
#define NH 32
#define NKV 8
#define HD 128
#define CTX 4096
#define NEWT 4095
#define CHUNK 512
#define NCH 8
#define SM_SCALE 0.08838834764831845f  // 1/sqrt(128)

// C[b][c] += sum_{k in chunk} A[b][k] * W[k][c].  A:(32,K) W:(K,N) row-major.
__global__ __launch_bounds__(256) void gemm32_kernel(
    const float* __restrict__ A, const float* __restrict__ W,
    float* __restrict__ C, int K, int N, int kchunk) {
  int c = blockIdx.x * 256 + threadIdx.x;
  int k0 = blockIdx.y * kchunk;
  float acc[BATCH];
#pragma unroll
  for (int b = 0; b < BATCH; ++b) acc[b] = 0.f;
  const float* Wp = W + (size_t)k0 * N + c;
  const float* Ap = A + k0;
#pragma unroll 4
  for (int k = 0; k < kchunk; ++k) {
    float wv = Wp[(size_t)k * N];
#pragma unroll
    for (int b = 0; b < BATCH; ++b)
      acc[b] += Ap[b * K + k] * wv;
  }
#pragma unroll
  for (int b = 0; b < BATCH; ++b) atomicAdd(&C[b * N + c], acc[b]);
}

__global__ __launch_bounds__(256) void rope_kernel(
    float* __restrict__ q, float* __restrict__ k,
    const float* __restrict__ cos_t, const float* __restrict__ sin_t) {
  int idx = blockIdx.x * 256 + threadIdx.x;
  int p = idx & 63;
  float c = cos_t[p], s = sin_t[p];
  float2 v = ((float2*)q)[idx];
  float2 o;
  o.x = v.x * c - v.y * s;
  o.y = v.x * s + v.y * c;
  ((float2*)q)[idx] = o;
  if (idx < BATCH * NKV * 64) {
    float2 vk = ((float2*)k)[idx];
    float2 ok;
    ok.x = vk.x * c - vk.y * s;
    ok.y = vk.x * s + vk.y * c;
    ((float2*)k)[idx] = ok;
  }
}

// Flash-decode partial: one block per (b, kv_head, chunk). 256 threads.
// Writes pm[blk*4+r], pl[blk*4+r], pacc[blk*512 + r*128 + d].
__global__ __launch_bounds__(256, 4) void attn_kernel(
    const float* __restrict__ q,
    const float* __restrict__ kcache,
    const float* __restrict__ vcache,
    const float* __restrict__ knew,
    const float* __restrict__ vnew,
    float* __restrict__ pm, float* __restrict__ pl,
    float* __restrict__ pacc) {
  __shared__ float sc[4 * CHUNK];   // 8 KB: scores/probs, then wave partials
  __shared__ float sml[8];          // m[4], l[4]
  int blk = blockIdx.x;
  int c = blk & 7, h = (blk >> 3) & 7, b = blk >> 6;
  int tid = threadIdx.x;
  int wave = tid >> 6, sub = tid & 63;
  int t_base = c * CHUNK;

  // ---- phase 1: scores ----
  int tg = tid >> 4;    // 0..15
  int lig = tid & 15;   // covers 8 d's
  float qreg[4][8];
#pragma unroll
  for (int r = 0; r < 4; ++r)
#pragma unroll
    for (int j = 0; j < 8; ++j)
      qreg[r][j] = q[b * (NH * HD) + (h * 4 + r) * HD + lig * 8 + j];

  const float* kbase = kcache + ((size_t)b * CTX * NKV + h) * HD;
  const float* knrow = knew + (b * NKV + h) * HD;
  for (int t0 = 0; t0 < CHUNK; t0 += 16) {
    int tl = t0 + tg;
    int t = t_base + tl;
    const float* krow = (t < NEWT) ? (kbase + (size_t)t * (NKV * HD)) : knrow;
    float4 ka = *(const float4*)(krow + lig * 8);
    float4 kb = *(const float4*)(krow + lig * 8 + 4);
#pragma unroll
    for (int r = 0; r < 4; ++r) {
      float part = ka.x * qreg[r][0] + ka.y * qreg[r][1] + ka.z * qreg[r][2] + ka.w * qreg[r][3]
                 + kb.x * qreg[r][4] + kb.y * qreg[r][5] + kb.z * qreg[r][6] + kb.w * qreg[r][7];
#pragma unroll
      for (int off = 8; off >= 1; off >>= 1)
        part += __shfl_xor(part, off);
      if (lig == 0) sc[r * CHUNK + tl] = part * SM_SCALE;
    }
  }
  __syncthreads();

  // ---- chunk softmax (unnormalized): wave r handles row r ----
  {
    int r = wave;
    float m = -1e30f;
    for (int i = sub; i < CHUNK; i += 64) m = fmaxf(m, sc[r * CHUNK + i]);
#pragma unroll
    for (int off = 32; off >= 1; off >>= 1) m = fmaxf(m, __shfl_xor(m, off));
    float ssum = 0.f;
    for (int i = sub; i < CHUNK; i += 64) {
      float pv = __expf(sc[r * CHUNK + i] - m);
      sc[r * CHUNK + i] = pv;
      ssum += pv;
    }
#pragma unroll
    for (int off = 32; off >= 1; off >>= 1) ssum += __shfl_xor(ssum, off);
    if (sub == 0) { sml[r] = m; sml[4 + r] = ssum; }
  }
  __syncthreads();
  if (tid < 4) {
    pm[blk * 4 + tid] = sml[tid];
    pl[blk * 4 + tid] = sml[4 + tid];
  }

  // ---- phase 2: acc[r][d] = sum_t p[r][t] * V[t][d] ----
  int dg = tid & 31;    // float4 index over d
  int tg2 = tid >> 5;   // 0..7
  float4 acc[4];
#pragma unroll
  for (int r = 0; r < 4; ++r) acc[r] = make_float4(0.f, 0.f, 0.f, 0.f);
  const float* vbase = vcache + ((size_t)b * CTX * NKV + h) * HD;
  const float* vnrow = vnew + (b * NKV + h) * HD;
  for (int t0 = 0; t0 < CHUNK; t0 += 8) {
    int tl = t0 + tg2;
    int t = t_base + tl;
    const float* vrow = (t < NEWT) ? (vbase + (size_t)t * (NKV * HD)) : vnrow;
    float4 vv = *(const float4*)(vrow + dg * 4);
#pragma unroll
    for (int r = 0; r < 4; ++r) {
      float pv = sc[r * CHUNK + tl];
      acc[r].x += pv * vv.x;
      acc[r].y += pv * vv.y;
      acc[r].z += pv * vv.z;
      acc[r].w += pv * vv.w;
    }
  }
  // fold the two half-waves (t-group pairs) together
#pragma unroll
  for (int r = 0; r < 4; ++r) {
    acc[r].x += __shfl_xor(acc[r].x, 32);
    acc[r].y += __shfl_xor(acc[r].y, 32);
    acc[r].z += __shfl_xor(acc[r].z, 32);
    acc[r].w += __shfl_xor(acc[r].w, 32);
  }
  __syncthreads();   // everyone done reading probs; reuse sc for wave partials
  if (sub < 32) {
#pragma unroll
    for (int r = 0; r < 4; ++r)
      *(float4*)&sc[wave * 512 + r * 128 + dg * 4] = acc[r];
  }
  __syncthreads();
#pragma unroll
  for (int rr = 0; rr < 2; ++rr) {
    int idx = tid + rr * 256;          // 0..511
    int r = idx >> 7, d = idx & 127;
    float s = sc[r * 128 + d] + sc[512 + r * 128 + d]
            + sc[1024 + r * 128 + d] + sc[1536 + r * 128 + d];
    pacc[(size_t)blk * 512 + r * 128 + d] = s;
  }
}

// out[b][h*4+r][d] = sum_c w_c*acc_c / sum_c w_c*l_c,  w_c = exp(m_c - M)
__global__ __launch_bounds__(256) void combine_kernel(
    const float* __restrict__ pm, const float* __restrict__ pl,
    const float* __restrict__ pacc, float* __restrict__ outa) {
  int idx = blockIdx.x * 256 + threadIdx.x;   // (b,h,r,d)
  int d = idx & 127, r = (idx >> 7) & 3, h = (idx >> 9) & 7, b = idx >> 12;
  int base = (b * 8 + h) * 8;
  float M = -1e30f;
#pragma unroll
  for (int c = 0; c < NCH; ++c) M = fmaxf(M, pm[(base + c) * 4 + r]);
  float num = 0.f, den = 0.f;
#pragma unroll
  for (int c = 0; c < NCH; ++c) {
    float w = __expf(pm[(base + c) * 4 + r] - M);
    den += w * pl[(base + c) * 4 + r];
    num += w * pacc[(size_t)(base + c) * 512 + r * 128 + d];
  }
  outa[b * (NH * HD) + (h * 4 + r) * HD + d] = num / den;
}

extern "C" void kernel_launch(void* const* d_in, const int* in_sizes, int n_in,
                              void* d_out, int out_size, void* d_ws, size_t ws_size,
                              hipStream_t stream) {
  const float* x  = (const float*)d_in[0];
  const float* wq = (const float*)d_in[1];
  const float* wk = (const float*)d_in[2];
  const float* wv = (const float*)d_in[3];
  const float* wo = (const float*)d_in[4];
  const float* ck = (const float*)d_in[5];
  const float* cv = (const float*)d_in[6];
  const float* fc = (const float*)d_in[7];
  const float* fs = (const float*)d_in[8];
  float* out = (float*)d_out;

  float* ws   = (float*)d_ws;
  float* ws_q = ws;              // 131072
  float* ws_k = ws + 131072;     // 32768
  float* ws_v = ws + 163840;     // 32768
  float* ws_a = ws + 196608;     // 131072 (fully written by combine)
  float* pm   = ws + 327680;     // 8192
  float* pl   = ws + 335872;     // 8192
  float* pacc = ws + 344064;     // 1048576 (fully written by attn)

  hipMemsetAsync(ws, 0, 196608 * sizeof(float), stream);
  hipMemsetAsync(d_out, 0, (size_t)out_size * sizeof(float), stream);

  gemm32_kernel<<<dim3(16, 32), 256, 0, stream>>>(x, wq, ws_q, DIM, NH * HD, 128);
  gemm32_kernel<<<dim3(4, 32), 256, 0, stream>>>(x, wk, ws_k, DIM, NKV * HD, 128);
  gemm32_kernel<<<dim3(4, 32), 256, 0, stream>>>(x, wv, ws_v, DIM, NKV * HD, 128);

  rope_kernel<<<256, 256, 0, stream>>>(ws_q, ws_k, fc, fs);

  attn_kernel<<<BATCH * NKV * NCH, 256, 0, stream>>>(ws_q, ck, cv, ws_k, ws_v, pm, pl, pacc);
  combine_kernel<<<512, 256, 0, stream>>>(pm, pl, pacc, ws_a);

  gemm32_kernel<<<dim3(16, 32), 256, 0, stream>>>(ws_a, wo, out, DIM, DIM, 128);
}

// Round 3
// 344.211 us; speedup vs baseline: 2.5573x; 1.6350x over previous
//
#include <hip/hip_runtime.h>

#define BATCH 32
#define DIM 4096
#define NH 32
#define NKV 8
#define HD 128
#define CTX 4096
#define NEWT 4095
#define CHUNK 512
#define NCH 8
#define NSPLIT 32
#define KCH (DIM / NSPLIT)   // 128
#define NQKV 6144            // 4096 q + 1024 k + 1024 v
#define SM_SCALE 0.08838834764831845f  // 1/sqrt(128)

// ---- stage 1: partial GEMM, no atomics ----
// part[(sy*BATCH + b)*NQKV + c] = sum_{k in chunk sy} x[b][k] * Wcat[k][c]
__global__ __launch_bounds__(256) void gemm_qkv_part(
    const float* __restrict__ A, const float* __restrict__ wq,
    const float* __restrict__ wk, const float* __restrict__ wv,
    float* __restrict__ part) {
  int bx = blockIdx.x;               // 0..23 (col block)
  int sy = blockIdx.y;               // 0..31 (k chunk)
  int cg = bx * 256 + threadIdx.x;   // global col 0..6143
  const float* W; int cw, Nw;
  if (bx < 16)      { W = wq; cw = cg;        Nw = 4096; }
  else if (bx < 20) { W = wk; cw = cg - 4096; Nw = 1024; }
  else              { W = wv; cw = cg - 5120; Nw = 1024; }
  int k0 = sy * KCH;
  float acc[BATCH];
#pragma unroll
  for (int b = 0; b < BATCH; ++b) acc[b] = 0.f;
  const float* Wp = W + (size_t)k0 * Nw + cw;
  const float* Ap = A + k0;
#pragma unroll 4
  for (int k = 0; k < KCH; ++k) {
    float wval = Wp[(size_t)k * Nw];
#pragma unroll
    for (int b = 0; b < BATCH; ++b)
      acc[b] += Ap[b * DIM + k] * wval;   // wave-uniform -> scalar loads
  }
#pragma unroll
  for (int b = 0; b < BATCH; ++b)
    part[((size_t)sy * BATCH + b) * NQKV + cg] = acc[b];
}

// ---- stage 2: reduce partials + RoPE, write q/k/v ----
__global__ __launch_bounds__(256) void qkv_reduce_rope(
    const float* __restrict__ part, const float* __restrict__ cos_t,
    const float* __restrict__ sin_t, float* __restrict__ q,
    float* __restrict__ k, float* __restrict__ v) {
  int idx = blockIdx.x * 256 + threadIdx.x;  // 0..98303  (32 b x 3072 pairs)
  int b = idx / 3072, c2 = idx - b * 3072;
  int c = c2 * 2;
  float s0 = 0.f, s1 = 0.f;
#pragma unroll 8
  for (int s = 0; s < NSPLIT; ++s) {
    float2 pv = *(const float2*)&part[((size_t)s * BATCH + b) * NQKV + c];
    s0 += pv.x; s1 += pv.y;
  }
  if (c < 4096) {
    int p = (c & 127) >> 1;
    float cc = cos_t[p], ss = sin_t[p];
    q[b * 4096 + c]     = s0 * cc - s1 * ss;
    q[b * 4096 + c + 1] = s0 * ss + s1 * cc;
  } else if (c < 5120) {
    int c0 = c - 4096;
    int p = (c0 & 127) >> 1;
    float cc = cos_t[p], ss = sin_t[p];
    k[b * 1024 + c0]     = s0 * cc - s1 * ss;
    k[b * 1024 + c0 + 1] = s0 * ss + s1 * cc;
  } else {
    int c0 = c - 5120;
    v[b * 1024 + c0]     = s0;
    v[b * 1024 + c0 + 1] = s1;
  }
}

// ---- flash-decode partial: one block per (b, kv_head, chunk) ----
__global__ __launch_bounds__(256, 2) void attn_kernel(
    const float* __restrict__ q,
    const float* __restrict__ kcache,
    const float* __restrict__ vcache,
    const float* __restrict__ knew,
    const float* __restrict__ vnew,
    float* __restrict__ pm, float* __restrict__ pl,
    float* __restrict__ pacc) {
  __shared__ float sc[4 * CHUNK];   // 8 KB
  __shared__ float sml[8];
  int blk = blockIdx.x;
  int c = blk & 7, h = (blk >> 3) & 7, b = blk >> 6;
  int tid = threadIdx.x;
  int wave = tid >> 6, sub = tid & 63;
  int t_base = c * CHUNK;

  // phase 1: scores
  int tg = tid >> 4;    // 0..15 t-rows per pass
  int lig = tid & 15;   // covers 8 d's
  float qreg[4][8];
#pragma unroll
  for (int r = 0; r < 4; ++r)
#pragma unroll
    for (int j = 0; j < 8; ++j)
      qreg[r][j] = q[b * (NH * HD) + (h * 4 + r) * HD + lig * 8 + j];

  const float* kbase = kcache + ((size_t)b * CTX * NKV + h) * HD;
  const float* knrow = knew + (b * NKV + h) * HD;
  for (int t0 = 0; t0 < CHUNK; t0 += 16) {
    int tl = t0 + tg;
    int t = t_base + tl;
    const float* krow = (t < NEWT) ? (kbase + (size_t)t * (NKV * HD)) : knrow;
    float4 ka = *(const float4*)(krow + lig * 8);
    float4 kb = *(const float4*)(krow + lig * 8 + 4);
#pragma unroll
    for (int r = 0; r < 4; ++r) {
      float part = ka.x * qreg[r][0] + ka.y * qreg[r][1] + ka.z * qreg[r][2] + ka.w * qreg[r][3]
                 + kb.x * qreg[r][4] + kb.y * qreg[r][5] + kb.z * qreg[r][6] + kb.w * qreg[r][7];
#pragma unroll
      for (int off = 8; off >= 1; off >>= 1)
        part += __shfl_xor(part, off);
      if (lig == 0) sc[r * CHUNK + tl] = part * SM_SCALE;
    }
  }
  __syncthreads();

  // chunk softmax (unnormalized), wave r handles row r
  {
    int r = wave;
    float m = -1e30f;
    for (int i = sub; i < CHUNK; i += 64) m = fmaxf(m, sc[r * CHUNK + i]);
#pragma unroll
    for (int off = 32; off >= 1; off >>= 1) m = fmaxf(m, __shfl_xor(m, off));
    float ssum = 0.f;
    for (int i = sub; i < CHUNK; i += 64) {
      float pv = __expf(sc[r * CHUNK + i] - m);
      sc[r * CHUNK + i] = pv;
      ssum += pv;
    }
#pragma unroll
    for (int off = 32; off >= 1; off >>= 1) ssum += __shfl_xor(ssum, off);
    if (sub == 0) { sml[r] = m; sml[4 + r] = ssum; }
  }
  __syncthreads();
  if (tid < 4) {
    pm[blk * 4 + tid] = sml[tid];
    pl[blk * 4 + tid] = sml[4 + tid];
  }

  // phase 2: acc[r][d] = sum_t p[r][t] * V[t][d]
  int dg = tid & 31;
  int tg2 = tid >> 5;   // 0..7
  float4 acc[4];
#pragma unroll
  for (int r = 0; r < 4; ++r) acc[r] = make_float4(0.f, 0.f, 0.f, 0.f);
  const float* vbase = vcache + ((size_t)b * CTX * NKV + h) * HD;
  const float* vnrow = vnew + (b * NKV + h) * HD;
  for (int t0 = 0; t0 < CHUNK; t0 += 8) {
    int tl = t0 + tg2;
    int t = t_base + tl;
    const float* vrow = (t < NEWT) ? (vbase + (size_t)t * (NKV * HD)) : vnrow;
    float4 vv = *(const float4*)(vrow + dg * 4);
#pragma unroll
    for (int r = 0; r < 4; ++r) {
      float pv = sc[r * CHUNK + tl];
      acc[r].x += pv * vv.x;
      acc[r].y += pv * vv.y;
      acc[r].z += pv * vv.z;
      acc[r].w += pv * vv.w;
    }
  }
#pragma unroll
  for (int r = 0; r < 4; ++r) {
    acc[r].x += __shfl_xor(acc[r].x, 32);
    acc[r].y += __shfl_xor(acc[r].y, 32);
    acc[r].z += __shfl_xor(acc[r].z, 32);
    acc[r].w += __shfl_xor(acc[r].w, 32);
  }
  __syncthreads();
  if (sub < 32) {
#pragma unroll
    for (int r = 0; r < 4; ++r)
      *(float4*)&sc[wave * 512 + r * 128 + dg * 4] = acc[r];
  }
  __syncthreads();
#pragma unroll
  for (int rr = 0; rr < 2; ++rr) {
    int idx = tid + rr * 256;
    int r = idx >> 7, d = idx & 127;
    float s = sc[r * 128 + d] + sc[512 + r * 128 + d]
            + sc[1024 + r * 128 + d] + sc[1536 + r * 128 + d];
    pacc[(size_t)blk * 512 + r * 128 + d] = s;
  }
}

__global__ __launch_bounds__(256) void combine_kernel(
    const float* __restrict__ pm, const float* __restrict__ pl,
    const float* __restrict__ pacc, float* __restrict__ outa) {
  int idx = blockIdx.x * 256 + threadIdx.x;
  int d = idx & 127, r = (idx >> 7) & 3, h = (idx >> 9) & 7, b = idx >> 12;
  int base = (b * 8 + h) * 8;
  float M = -1e30f;
#pragma unroll
  for (int c = 0; c < NCH; ++c) M = fmaxf(M, pm[(base + c) * 4 + r]);
  float num = 0.f, den = 0.f;
#pragma unroll
  for (int c = 0; c < NCH; ++c) {
    float w = __expf(pm[(base + c) * 4 + r] - M);
    den += w * pl[(base + c) * 4 + r];
    num += w * pacc[(size_t)(base + c) * 512 + r * 128 + d];
  }
  outa[b * (NH * HD) + (h * 4 + r) * HD + d] = num / den;
}

// ---- wo projection: stage 1 partials ----
__global__ __launch_bounds__(256) void gemm_wo_part(
    const float* __restrict__ A, const float* __restrict__ W,
    float* __restrict__ part) {
  int c = blockIdx.x * 256 + threadIdx.x;  // 0..4095
  int sy = blockIdx.y;                     // 0..31
  int k0 = sy * KCH;
  float acc[BATCH];
#pragma unroll
  for (int b = 0; b < BATCH; ++b) acc[b] = 0.f;
  const float* Wp = W + (size_t)k0 * DIM + c;
  const float* Ap = A + k0;
#pragma unroll 4
  for (int k = 0; k < KCH; ++k) {
    float wval = Wp[(size_t)k * DIM];
#pragma unroll
    for (int b = 0; b < BATCH; ++b)
      acc[b] += Ap[b * DIM + k] * wval;
  }
#pragma unroll
  for (int b = 0; b < BATCH; ++b)
    part[((size_t)sy * BATCH + b) * DIM + c] = acc[b];
}

__global__ __launch_bounds__(256) void wo_reduce(
    const float* __restrict__ part, float* __restrict__ out) {
  int idx = blockIdx.x * 256 + threadIdx.x;  // 0..65535 (32 b x 2048 pairs)
  int b = idx >> 11, c2 = idx & 2047;
  int c = c2 * 2;
  float s0 = 0.f, s1 = 0.f;
#pragma unroll 8
  for (int s = 0; s < NSPLIT; ++s) {
    float2 pv = *(const float2*)&part[((size_t)s * BATCH + b) * DIM + c];
    s0 += pv.x; s1 += pv.y;
  }
  out[b * DIM + c]     = s0;
  out[b * DIM + c + 1] = s1;
}

extern "C" void kernel_launch(void* const* d_in, const int* in_sizes, int n_in,
                              void* d_out, int out_size, void* d_ws, size_t ws_size,
                              hipStream_t stream) {
  const float* x  = (const float*)d_in[0];
  const float* wq = (const float*)d_in[1];
  const float* wk = (const float*)d_in[2];
  const float* wv = (const float*)d_in[3];
  const float* wo = (const float*)d_in[4];
  const float* ck = (const float*)d_in[5];
  const float* cv = (const float*)d_in[6];
  const float* fc = (const float*)d_in[7];
  const float* fs = (const float*)d_in[8];
  float* out = (float*)d_out;

  float* ws    = (float*)d_ws;
  float* ws_q  = ws;               // 131072
  float* ws_k  = ws + 131072;      // 32768
  float* ws_v  = ws + 163840;      // 32768
  float* ws_a  = ws + 196608;      // 131072
  float* pm    = ws + 327680;      // 8192
  float* pl    = ws + 335872;      // 8192
  float* pacc  = ws + 344064;      // 1048576
  float* partq = ws + 1392640;     // 32*32*6144 = 6291456
  float* parto = ws + 7684096;     // 32*32*4096 = 4194304
  // total 11878400 floats ~= 47.5 MB

  gemm_qkv_part<<<dim3(24, NSPLIT), 256, 0, stream>>>(x, wq, wk, wv, partq);
  qkv_reduce_rope<<<384, 256, 0, stream>>>(partq, fc, fs, ws_q, ws_k, ws_v);

  attn_kernel<<<BATCH * NKV * NCH, 256, 0, stream>>>(ws_q, ck, cv, ws_k, ws_v, pm, pl, pacc);
  combine_kernel<<<512, 256, 0, stream>>>(pm, pl, pacc, ws_a);

  gemm_wo_part<<<dim3(16, NSPLIT), 256, 0, stream>>>(ws_a, wo, parto);
  wo_reduce<<<256, 256, 0, stream>>>(parto, out);
}